// Round 12
// baseline (107.576 us; speedup 1.0000x reference)
//
#include <hip/hip_runtime.h>
#include <hip/hip_bf16.h>
#include <hip/hip_fp16.h>
#include <math.h>

// GCN 2-layer on MI355X. Round 12: multi-copy LDS histograms in bin (x4) and
// sort (x2) to cut same-bin atomic contention + bank aliasing; float4
// self-row loads in scatter epilogues. fp16 h1/h3 storage as round 11.

#define FIN 128
#define FMID 16
#define FOUT 7

#define LBITS 7
#define NPB   128            // nodes per bucket = 1<<LBITS
#define SBITS 17
#define SMASK 0x1FFFF
#define NB_MAX 800           // max buckets (n<=102400)
#define CAP   5120           // words per bucket; mean 4092, sigma ~64
#define EPT   12             // edges per thread in bin kernel
#define BINT  1024
#define TILE  (EPT * BINT)   // 12288 edges per block

#define G1N   128            // gemm1 nodes per block
#define AS1   17             // scatter1 acc2 stride (odd -> conflict-free)
#define AS2   9              // scatter2 acc2 stride

__global__ void zero_kernel(int* __restrict__ p, int m) {
    int i = blockIdx.x * 256 + threadIdx.x;
    if (i < m) p[i] = 0;
}

// unpack a 16B vector of 8 halfs and accumulate into 8 fp32 accumulators
__device__ inline void addh8(float* a, float4 v) {
    const __half2* h = (const __half2*)&v;
#pragma unroll
    for (int k = 0; k < 4; ++k) {
        float2 f = __half22float2(h[k]);
        a[2 * k]     += f.x;
        a[2 * k + 1] += f.y;
    }
}

// ==================== bucket sort of edges (4-copy histogram) ====================
__global__ __launch_bounds__(BINT) void bin_kernel(const int* __restrict__ src,
                                                   const int* __restrict__ dst,
                                                   int* __restrict__ pairs,
                                                   int* __restrict__ gcnt,
                                                   int e, int nb) {
    __shared__ int sorted[TILE];                      // 48KB
    __shared__ int cnt4[NB_MAX * 4];                  // 12.8KB
    __shared__ int lofs4[NB_MAX * 4];                 // 12.8KB
    __shared__ int excl[NB_MAX], gbase[NB_MAX];       // 6.4KB
    __shared__ int wsum[16];
    int tid = threadIdx.x;
    int cc = tid & 3;
    for (int j = tid; j < nb * 4; j += BINT) cnt4[j] = 0;
    __syncthreads();

    int base = blockIdx.x * TILE;
    int w[EPT], bk[EPT];
#pragma unroll
    for (int k = 0; k < EPT; ++k) {
        int idx = base + k * BINT + tid;
        if (idx < e) {
            int d = dst[idx], s = src[idx];
            w[k]  = ((d & (NPB - 1)) << SBITS) | s;   // 7+17 = 24 bits
            bk[k] = d >> LBITS;
            atomicAdd(&cnt4[bk[k] * 4 + cc], 1);
        } else bk[k] = -1;
    }
    __syncthreads();

    int tot = 0;
    if (tid < nb) {
        tot = cnt4[tid * 4] + cnt4[tid * 4 + 1] + cnt4[tid * 4 + 2] + cnt4[tid * 4 + 3];
        if (tot > 0) gbase[tid] = atomicAdd(&gcnt[tid], tot);
    }

    // exclusive scan of tot -> excl
    {
        int v = (tid < nb) ? tot : 0;
        int lane = tid & 63, wid = tid >> 6;
        int incl = v;
#pragma unroll
        for (int d = 1; d < 64; d <<= 1) {
            int t = __shfl_up(incl, d);
            if (lane >= d) incl += t;
        }
        if (lane == 63) wsum[wid] = incl;
        __syncthreads();
        if (tid < 16) {
            int wv = wsum[tid];
            int wincl = wv;
#pragma unroll
            for (int d = 1; d < 16; d <<= 1) {
                int t = __shfl_up(wincl, d);
                if (tid >= d) wincl += t;
            }
            wsum[tid] = wincl - wv;
        }
        __syncthreads();
        if (tid < nb) excl[tid] = wsum[wid] + incl - v;
    }
    __syncthreads();

    // per-copy placement bases
    if (tid < nb) {
        int b0 = excl[tid];
        int c0 = cnt4[tid * 4], c1 = cnt4[tid * 4 + 1], c2 = cnt4[tid * 4 + 2];
        lofs4[tid * 4 + 0] = b0;
        lofs4[tid * 4 + 1] = b0 + c0;
        lofs4[tid * 4 + 2] = b0 + c0 + c1;
        lofs4[tid * 4 + 3] = b0 + c0 + c1 + c2;
    }
    __syncthreads();

#pragma unroll
    for (int k = 0; k < EPT; ++k) {
        if (bk[k] >= 0) {
            int pos = atomicAdd(&lofs4[bk[k] * 4 + cc], 1);
            sorted[pos] = w[k];
        }
    }
    __syncthreads();

    // coalesced copy-out: one 16-lane group per bucket round-robin.
    // lofs4[4j+3] now equals excl[j] + count.
    int g16 = tid >> 4, l16 = tid & 15;               // 64 groups
    for (int j = g16; j < nb; j += 64) {
        int st = excl[j];
        int c  = lofs4[j * 4 + 3] - st;
        if (!c) continue;
        int gb = gbase[j];
        size_t go = (size_t)j * CAP;
        for (int l = l16; l < c; l += 16)
            if (gb + l < CAP) pairs[go + gb + l] = sorted[st + l];
    }
}

// ==================== per-bucket sort by local dst (2-copy histogram) ====================
__global__ __launch_bounds__(512) void sort_kernel(int* __restrict__ pairs,
                                                   const int* __restrict__ gcnt,
                                                   int* __restrict__ rs_g,
                                                   float* __restrict__ dinv, int n) {
    __shared__ int praw[CAP];                // 20KB
    __shared__ int slist[CAP];               // 20KB
    __shared__ int cnt2[NPB * 2], lofs2[NPB * 2], rowstart[NPB];
    __shared__ int wtot_s;
    int tid = threadIdx.x, b = blockIdx.x;
    int cc = tid & 1;
    if (tid < NPB * 2) cnt2[tid] = 0;
    __syncthreads();

    int c = min(gcnt[b], CAP);
    size_t go = (size_t)b * CAP;

    for (int i = tid; i < c; i += 512) {
        int w = pairs[go + i];
        praw[i] = w;
        atomicAdd(&cnt2[(w >> SBITS) * 2 + cc], 1);
    }
    __syncthreads();

    int v = 0, incl = 0;
    if (tid < NPB) {
        v = cnt2[tid * 2] + cnt2[tid * 2 + 1];
        incl = v;
        int lane = tid & 63;
#pragma unroll
        for (int d = 1; d < 64; d <<= 1) {
            int t = __shfl_up(incl, d);
            if (lane >= d) incl += t;
        }
        if (tid == 63) wtot_s = incl;
    }
    __syncthreads();
    if (tid < NPB) {
        int ex = incl - v + ((tid >= 64) ? wtot_s : 0);
        rowstart[tid] = ex;
        lofs2[tid * 2]     = ex;
        lofs2[tid * 2 + 1] = ex + cnt2[tid * 2];
    }
    __syncthreads();

    for (int i = tid; i < c; i += 512) {
        int w = praw[i];
        int pos = atomicAdd(&lofs2[(w >> SBITS) * 2 + cc], 1);
        slist[pos] = w & SMASK;
    }
    __syncthreads();

    for (int i = tid; i < c; i += 512) pairs[go + i] = slist[i];
    if (tid < NPB) {
        rs_g[b * NPB + tid] = rowstart[tid];
        int node = b * NPB + tid;
        if (node < n) dinv[node] = rsqrtf((float)v + 1.0f);
    }
}

// ==================== GEMM1: h1h = half(x @ W1 * dinv[row]) ====================
__global__ __launch_bounds__(256) void gemm1_kernel(const float* __restrict__ x,
                                                    const float* __restrict__ W,
                                                    const float* __restrict__ dinv,
                                                    __half* __restrict__ h1h, int n,
                                                    int sentinel) {
    __shared__ float WsT[16 * 132];      // [f][k] stride 132 (8.4KB)
    int tid = threadIdx.x;
    int n0 = blockIdx.x * G1N;

    for (int i = tid; i < FIN * FMID; i += 256) {
        int k = i >> 4, f = i & 15;
        WsT[f * 132 + k] = W[i];
    }
    __syncthreads();

    int ngrp = tid >> 3;       // 0..31
    int fh = tid & 7;          // half2 slot; features 2fh, 2fh+1
    int r0 = n0 + ngrp, r1 = r0 + 32, r2 = r0 + 64, r3 = r0 + 96;
    int nc = n - 1;
    size_t c0 = (size_t)min(r0, nc) * 32;
    size_t c1 = (size_t)min(r1, nc) * 32;
    size_t c2 = (size_t)min(r2, nc) * 32;
    size_t c3 = (size_t)min(r3, nc) * 32;

    const float4* x4  = (const float4*)x;
    const float4* wa4 = (const float4*)(WsT + (2 * fh) * 132);
    const float4* wb4 = (const float4*)(WsT + (2 * fh + 1) * 132);

    float a0 = 0.f, a1 = 0.f, a2 = 0.f, a3 = 0.f;
    float b0 = 0.f, b1_ = 0.f, b2_ = 0.f, b3 = 0.f;

#pragma unroll 8
    for (int ck = 0; ck < 32; ++ck) {
        float4 x0 = x4[c0 + ck];
        float4 x1 = x4[c1 + ck];
        float4 x2 = x4[c2 + ck];
        float4 x3 = x4[c3 + ck];
        float4 wa = wa4[ck];
        float4 wb = wb4[ck];
        a0 += x0.x * wa.x + x0.y * wa.y + x0.z * wa.z + x0.w * wa.w;
        a1 += x1.x * wa.x + x1.y * wa.y + x1.z * wa.z + x1.w * wa.w;
        a2 += x2.x * wa.x + x2.y * wa.y + x2.z * wa.z + x2.w * wa.w;
        a3 += x3.x * wa.x + x3.y * wa.y + x3.z * wa.z + x3.w * wa.w;
        b0  += x0.x * wb.x + x0.y * wb.y + x0.z * wb.z + x0.w * wb.w;
        b1_ += x1.x * wb.x + x1.y * wb.y + x1.z * wb.z + x1.w * wb.w;
        b2_ += x2.x * wb.x + x2.y * wb.y + x2.z * wb.z + x2.w * wb.w;
        b3  += x3.x * wb.x + x3.y * wb.y + x3.z * wb.z + x3.w * wb.w;
    }

    float ra[4] = {a0, a1, a2, a3};
    float rb[4] = {b0, b1_, b2_, b3};
    int rr[4] = {r0, r1, r2, r3};
    __half2* h2 = (__half2*)h1h;
#pragma unroll
    for (int i = 0; i < 4; ++i) {
        int node = rr[i];
        if (node < n) {
            float dd = dinv ? dinv[node] : 1.0f;
            h2[(size_t)node * 8 + fh] = __floats2half2_rn(ra[i] * dd, rb[i] * dd);
        } else if (node == n && sentinel) {
            h2[(size_t)n * 8 + fh] = __floats2half2_rn(0.0f, 0.0f);
        }
    }
}

// ==================== scatter1: fp16 gather + fused epilogue ====================
__global__ __launch_bounds__(512) void scatter1_kernel(const int* __restrict__ pairs,
                                                       const int* __restrict__ gcnt,
                                                       const int* __restrict__ rs_g,
                                                       const float* __restrict__ dinv,
                                                       const __half* __restrict__ h1h,
                                                       const float* __restrict__ b1,
                                                       const float* __restrict__ W2,
                                                       __half* __restrict__ h3h, int n) {
    __shared__ int   slist[CAP + 8];
    __shared__ int   rowstart_s[NPB + 1];
    __shared__ float acc2[NPB * AS1];        // stride 17
    __shared__ float W2s[FMID * FOUT];
    __shared__ float b1s[FMID];
    int tid = threadIdx.x, b = blockIdx.x;
    int c = min(gcnt[b], CAP);
    size_t go = (size_t)b * CAP;

    if (tid < FMID * FOUT) W2s[tid] = W2[tid];
    if (tid < FMID) b1s[tid] = b1[tid];
    if (tid < NPB) rowstart_s[tid] = rs_g[b * NPB + tid];
    if (tid == 0) rowstart_s[NPB] = c;
    for (int i = tid; i < c; i += 512) slist[i] = pairs[go + i];
    __syncthreads();

    {
        int nd = tid >> 2, l = tid & 3;
        int eo = l >> 1, half = l & 1;
        int pbeg = rowstart_s[nd];
        int pend = rowstart_s[nd + 1];
        const float4* h4 = (const float4*)h1h;   // 2 x 16B per 32B row
        float acc[8];
#pragma unroll
        for (int k = 0; k < 8; ++k) acc[k] = 0.0f;
        for (int p = pbeg + eo; p < pend; p += 8) {
            int i0 = slist[p];
            int i1 = (p + 2 < pend) ? slist[p + 2] : n;
            int i2 = (p + 4 < pend) ? slist[p + 4] : n;
            int i3 = (p + 6 < pend) ? slist[p + 6] : n;
            float4 v0 = h4[(size_t)i0 * 2 + half];
            float4 v1 = h4[(size_t)i1 * 2 + half];
            float4 v2 = h4[(size_t)i2 * 2 + half];
            float4 v3 = h4[(size_t)i3 * 2 + half];
            addh8(acc, v0);
            addh8(acc, v1);
            addh8(acc, v2);
            addh8(acc, v3);
        }
#pragma unroll
        for (int k = 0; k < 8; ++k) acc[k] += __shfl_xor(acc[k], 2);
        if (eo == 0) {
            float* ap = acc2 + nd * AS1 + half * 8;
#pragma unroll
            for (int k = 0; k < 8; ++k) ap[k] = acc[k];
        }
    }
    __syncthreads();

    int node = b * NPB + tid;
    if (tid < NPB && node < n) {
        float dd = dinv[node];
        // self row: two float4 loads + unpack
        float4 sr0 = ((const float4*)h1h)[(size_t)node * 2 + 0];
        float4 sr1 = ((const float4*)h1h)[(size_t)node * 2 + 1];
        float fself[FMID];
        {
            const __half2* ha = (const __half2*)&sr0;
            const __half2* hb = (const __half2*)&sr1;
#pragma unroll
            for (int k = 0; k < 4; ++k) {
                float2 fa = __half22float2(ha[k]);
                float2 fb = __half22float2(hb[k]);
                fself[2 * k]     = fa.x;
                fself[2 * k + 1] = fa.y;
                fself[8 + 2 * k]     = fb.x;
                fself[8 + 2 * k + 1] = fb.y;
            }
        }
        float vbuf[FMID];
#pragma unroll
        for (int k = 0; k < FMID; ++k) {
            float t = dd * (acc2[tid * AS1 + k] + fself[k]) + b1s[k];
            vbuf[k] = t > 0.0f ? t : 0.0f;
        }
        float sj[8];
#pragma unroll
        for (int j = 0; j < FOUT; ++j) {
            float s = 0.0f;
#pragma unroll
            for (int k = 0; k < FMID; ++k) s += vbuf[k] * W2s[k * FOUT + j];
            sj[j] = s * dd;
        }
        float4 st;
        __half2* sp = (__half2*)&st;
        sp[0] = __floats2half2_rn(sj[0], sj[1]);
        sp[1] = __floats2half2_rn(sj[2], sj[3]);
        sp[2] = __floats2half2_rn(sj[4], sj[5]);
        sp[3] = __floats2half2_rn(sj[6], 0.0f);
        ((float4*)h3h)[node] = st;               // 16B row
    } else if (tid < NPB && node == n) {
        ((float4*)h3h)[n] = make_float4(0.f, 0.f, 0.f, 0.f);
    }
}

// ==================== scatter2: fp16 gather + log_softmax ====================
__global__ __launch_bounds__(512) void scatter2_kernel(const int* __restrict__ pairs,
                                                       const int* __restrict__ gcnt,
                                                       const int* __restrict__ rs_g,
                                                       const float* __restrict__ dinv,
                                                       const __half* __restrict__ h3h,
                                                       const float* __restrict__ b2,
                                                       float* __restrict__ out, int n) {
    __shared__ int   slist[CAP + 8];
    __shared__ int   rowstart_s[NPB + 1];
    __shared__ float acc2[NPB * AS2];        // stride 9
    __shared__ float b2s[8];
    int tid = threadIdx.x, b = blockIdx.x;
    int c = min(gcnt[b], CAP);
    size_t go = (size_t)b * CAP;

    if (tid < FOUT) b2s[tid] = b2[tid];
    if (tid < NPB) rowstart_s[tid] = rs_g[b * NPB + tid];
    if (tid == 0) rowstart_s[NPB] = c;
    for (int i = tid; i < c; i += 512) slist[i] = pairs[go + i];
    __syncthreads();

    {
        int nd = tid >> 2, l = tid & 3;
        int pbeg = rowstart_s[nd];
        int pend = rowstart_s[nd + 1];
        const float4* h4 = (const float4*)h3h;   // 16B per row
        float acc[8];
#pragma unroll
        for (int k = 0; k < 8; ++k) acc[k] = 0.0f;
        for (int p = pbeg + l; p < pend; p += 8) {
            int i0 = slist[p];
            int i1 = (p + 4 < pend) ? slist[p + 4] : n;
            float4 v0 = h4[i0];
            float4 v1 = h4[i1];
            addh8(acc, v0);
            addh8(acc, v1);
        }
#pragma unroll
        for (int k = 0; k < 8; ++k) {
            acc[k] += __shfl_xor(acc[k], 1);
            acc[k] += __shfl_xor(acc[k], 2);
        }
        if (l == 0) {
            float* ap = acc2 + nd * AS2;
#pragma unroll
            for (int k = 0; k < 8; ++k) ap[k] = acc[k];
        }
    }
    __syncthreads();

    int node = b * NPB + tid;
    if (tid < NPB && node < n) {
        float dd = dinv[node];
        float4 sv = ((const float4*)h3h)[node];
        float hself[8];
        {
            const __half2* h = (const __half2*)&sv;
#pragma unroll
            for (int k = 0; k < 4; ++k) {
                float2 f2v = __half22float2(h[k]);
                hself[2 * k] = f2v.x;
                hself[2 * k + 1] = f2v.y;
            }
        }
        float t[FOUT], m = -INFINITY;
#pragma unroll
        for (int j = 0; j < FOUT; ++j) {
            t[j] = dd * (acc2[tid * AS2 + j] + hself[j]) + b2s[j];
            m = fmaxf(m, t[j]);
        }
        float sum = 0.0f;
#pragma unroll
        for (int j = 0; j < FOUT; ++j) sum += expf(t[j] - m);
        float lse = logf(sum);
#pragma unroll
        for (int j = 0; j < FOUT; ++j) out[(size_t)node * FOUT + j] = t[j] - m - lse;
    }
}

// ==================== fallback (fp32 atomic path) ====================
__global__ void fb_gemm1_kernel(const float* __restrict__ x, const float* __restrict__ W,
                                float* __restrict__ h1, int n) {
    int i = blockIdx.x * blockDim.x + threadIdx.x;
    if (i >= n * FMID) return;
    int node = i >> 4, f = i & 15;
    float s = 0.0f;
    for (int k = 0; k < FIN; ++k) s += x[(size_t)node * FIN + k] * W[k * FMID + f];
    h1[i] = s;
}
__global__ void fb_deg_kernel(const int* __restrict__ dst, float* __restrict__ deg, int e) {
    int i = blockIdx.x * blockDim.x + threadIdx.x;
    if (i < e) atomicAdd(&deg[dst[i]], 1.0f);
}
__global__ void fb_dinv_kernel(float* __restrict__ deg, int n) {
    int i = blockIdx.x * blockDim.x + threadIdx.x;
    if (i < n) deg[i] = rsqrtf(deg[i] + 1.0f);
}
__global__ void fb_scatter1_kernel(const int* __restrict__ src, const int* __restrict__ dst,
                                   const float* __restrict__ dinv, const float* __restrict__ h1,
                                   float* __restrict__ out1, int e) {
    int i = blockIdx.x * blockDim.x + threadIdx.x;
    if (i >= e) return;
    int s = src[i], d = dst[i];
    float norm = dinv[s] * dinv[d];
    const float4* hs = (const float4*)(h1 + (size_t)s * FMID);
    float* o = out1 + (size_t)d * FMID;
#pragma unroll
    for (int q = 0; q < 4; ++q) {
        float4 vv = hs[q];
        atomicAdd(o + q * 4 + 0, vv.x * norm);
        atomicAdd(o + q * 4 + 1, vv.y * norm);
        atomicAdd(o + q * 4 + 2, vv.z * norm);
        atomicAdd(o + q * 4 + 3, vv.w * norm);
    }
}
__global__ void fb_layer2_kernel(const float* __restrict__ agg, const float* __restrict__ h1,
                                 const float* __restrict__ dinv, const float* __restrict__ b1,
                                 const float* __restrict__ W2, float* __restrict__ h3, int n) {
    int i = blockIdx.x * blockDim.x + threadIdx.x;
    if (i >= n) return;
    float dii = dinv[i] * dinv[i];
    float v[FMID];
#pragma unroll
    for (int k = 0; k < FMID; ++k) {
        float t = agg[(size_t)i * FMID + k] + h1[(size_t)i * FMID + k] * dii + b1[k];
        v[k] = t > 0.0f ? t : 0.0f;
    }
#pragma unroll
    for (int j = 0; j < FOUT; ++j) {
        float s = 0.0f;
#pragma unroll
        for (int k = 0; k < FMID; ++k) s += v[k] * W2[k * FOUT + j];
        h3[(size_t)i * FOUT + j] = s;
    }
}
__global__ void fb_scatter2_kernel(const int* __restrict__ src, const int* __restrict__ dst,
                                   const float* __restrict__ dinv, const float* __restrict__ h3,
                                   float* __restrict__ out2, int e) {
    int i = blockIdx.x * blockDim.x + threadIdx.x;
    if (i >= e) return;
    int s = src[i], d = dst[i];
    float norm = dinv[s] * dinv[d];
    const float* hs = h3 + (size_t)s * FOUT;
    float* o = out2 + (size_t)d * FOUT;
#pragma unroll
    for (int j = 0; j < FOUT; ++j) atomicAdd(o + j, hs[j] * norm);
}
__global__ void fb_finalize_kernel(const float* __restrict__ agg2, const float* __restrict__ h3,
                                   const float* __restrict__ dinv, const float* __restrict__ b2,
                                   float* __restrict__ out, int n) {
    int i = blockIdx.x * blockDim.x + threadIdx.x;
    if (i >= n) return;
    float dii = dinv[i] * dinv[i];
    float t[FOUT], m = -INFINITY;
#pragma unroll
    for (int j = 0; j < FOUT; ++j) {
        t[j] = agg2[(size_t)i * FOUT + j] + h3[(size_t)i * FOUT + j] * dii + b2[j];
        m = fmaxf(m, t[j]);
    }
    float sum = 0.0f;
#pragma unroll
    for (int j = 0; j < FOUT; ++j) sum += expf(t[j] - m);
    float lse = logf(sum);
#pragma unroll
    for (int j = 0; j < FOUT; ++j) out[(size_t)i * FOUT + j] = t[j] - m - lse;
}

extern "C" void kernel_launch(void* const* d_in, const int* in_sizes, int n_in,
                              void* d_out, int out_size, void* d_ws, size_t ws_size,
                              hipStream_t stream) {
    const float* x  = (const float*)d_in[0];
    const int*   ei = (const int*)d_in[1];
    const float* W1 = (const float*)d_in[2];
    const float* b1 = (const float*)d_in[3];
    const float* W2 = (const float*)d_in[4];
    const float* b2 = (const float*)d_in[5];

    const int n = in_sizes[0] / FIN;   // 100000
    const int e = in_sizes[1] / 2;     // 3200000
    const int* src = ei;
    const int* dst = ei + e;

    const int nb  = (n + NPB - 1) / NPB;
    const int nb2 = (n + 1 + NPB - 1) / NPB;

    size_t need = ((size_t)NB_MAX + (size_t)nb * CAP + (size_t)n +
                   (size_t)nb2 * NPB + (size_t)8 * (n + 1) + (size_t)4 * (n + 1)) * 4;

    if (nb2 <= NB_MAX && n + 1 < (1 << SBITS) && ws_size >= need) {
        int*    gcnt  = (int*)d_ws;
        int*    pairs = gcnt + NB_MAX;
        float*  dinv  = (float*)(pairs + (size_t)nb * CAP);
        int*    rs_g  = (int*)(dinv + n);
        __half* h1h   = (__half*)(rs_g + (size_t)nb2 * NPB);
        __half* h3h   = h1h + (size_t)16 * (n + 1);

        zero_kernel<<<(NB_MAX + 255) / 256, 256, 0, stream>>>(gcnt, NB_MAX);

        int gridBin = (e + TILE - 1) / TILE;
        bin_kernel<<<gridBin, BINT, 0, stream>>>(src, dst, pairs, gcnt, e, nb);
        sort_kernel<<<nb, 512, 0, stream>>>(pairs, gcnt, rs_g, dinv, n);
        gemm1_kernel<<<nb2, 256, 0, stream>>>(x, W1, dinv, h1h, n, 1);
        scatter1_kernel<<<nb2, 512, 0, stream>>>(pairs, gcnt, rs_g, dinv, h1h, b1, W2, h3h, n);
        scatter2_kernel<<<nb, 512, 0, stream>>>(pairs, gcnt, rs_g, dinv, h3h, b2, (float*)d_out, n);
    } else {
        // fallback: fp32 atomic path (47n floats)
        float* ws   = (float*)d_ws;
        float* deg  = ws;
        float* out1 = ws + (size_t)n;
        float* out2 = ws + (size_t)17 * n;
        float* h1   = ws + (size_t)24 * n;
        float* h3   = ws + (size_t)40 * n;

        hipMemsetAsync(ws, 0, (size_t)24 * n * sizeof(float), stream);

        const int B = 256;
        const int gridE = (e + B - 1) / B;
        const int gridN = (n + B - 1) / B;
        fb_deg_kernel<<<gridE, B, 0, stream>>>(dst, deg, e);
        fb_dinv_kernel<<<gridN, B, 0, stream>>>(deg, n);
        fb_gemm1_kernel<<<(n * FMID + B - 1) / B, B, 0, stream>>>(x, W1, h1, n);
        fb_scatter1_kernel<<<gridE, B, 0, stream>>>(src, dst, deg, h1, out1, e);
        fb_layer2_kernel<<<gridN, B, 0, stream>>>(out1, h1, deg, b1, W2, h3, n);
        fb_scatter2_kernel<<<gridE, B, 0, stream>>>(src, dst, deg, h3, out2, e);
        fb_finalize_kernel<<<gridN, B, 0, stream>>>(out2, h3, deg, b2, (float*)d_out, n);
    }
}

// Round 13
// 104.471 us; speedup vs baseline: 1.0297x; 1.0297x over previous
//
#include <hip/hip_runtime.h>
#include <hip/hip_bf16.h>
#include <hip/hip_fp16.h>
#include <math.h>

// GCN 2-layer on MI355X. Round 13: bin reverted to 1-copy histogram (61KB LDS
// -> 2 blocks/CU); sort drops praw staging (reads pairs twice from global,
// LDS 23KB -> full occupancy). Scatters/gemm1 frozen from round 12.

#define FIN 128
#define FMID 16
#define FOUT 7

#define LBITS 7
#define NPB   128            // nodes per bucket = 1<<LBITS
#define SBITS 17
#define SMASK 0x1FFFF
#define NB_MAX 800           // max buckets (n<=102400)
#define CAP   5120           // words per bucket; mean 4092, sigma ~64
#define EPT   12             // edges per thread in bin kernel
#define BINT  1024
#define TILE  (EPT * BINT)   // 12288 edges per block

#define G1N   128            // gemm1 nodes per block
#define AS1   17             // scatter1 acc2 stride (odd -> conflict-free)
#define AS2   9              // scatter2 acc2 stride

__global__ void zero_kernel(int* __restrict__ p, int m) {
    int i = blockIdx.x * 256 + threadIdx.x;
    if (i < m) p[i] = 0;
}

// unpack a 16B vector of 8 halfs and accumulate into 8 fp32 accumulators
__device__ inline void addh8(float* a, float4 v) {
    const __half2* h = (const __half2*)&v;
#pragma unroll
    for (int k = 0; k < 4; ++k) {
        float2 f = __half22float2(h[k]);
        a[2 * k]     += f.x;
        a[2 * k + 1] += f.y;
    }
}

// ==================== bucket sort of edges (1-copy, 61KB LDS) ====================
__global__ __launch_bounds__(BINT) void bin_kernel(const int* __restrict__ src,
                                                   const int* __restrict__ dst,
                                                   int* __restrict__ pairs,
                                                   int* __restrict__ gcnt,
                                                   int e, int nb) {
    __shared__ int sorted[TILE];                      // 48KB
    __shared__ int cnt[NB_MAX], excl[NB_MAX], lofs[NB_MAX], gbase[NB_MAX];
    __shared__ int wsum[16];
    int tid = threadIdx.x;
    for (int j = tid; j < nb; j += BINT) cnt[j] = 0;
    __syncthreads();

    int base = blockIdx.x * TILE;
    int w[EPT], bk[EPT];
#pragma unroll
    for (int k = 0; k < EPT; ++k) {
        int idx = base + k * BINT + tid;
        if (idx < e) {
            int d = dst[idx], s = src[idx];
            w[k]  = ((d & (NPB - 1)) << SBITS) | s;   // 7+17 = 24 bits
            bk[k] = d >> LBITS;
            atomicAdd(&cnt[bk[k]], 1);
        } else bk[k] = -1;
    }
    __syncthreads();

    if (tid < nb && cnt[tid] > 0) gbase[tid] = atomicAdd(&gcnt[tid], cnt[tid]);

    // exclusive scan cnt -> excl
    {
        int v = (tid < nb) ? cnt[tid] : 0;
        int lane = tid & 63, wid = tid >> 6;
        int incl = v;
#pragma unroll
        for (int d = 1; d < 64; d <<= 1) {
            int t = __shfl_up(incl, d);
            if (lane >= d) incl += t;
        }
        if (lane == 63) wsum[wid] = incl;
        __syncthreads();
        if (tid < 16) {
            int wv = wsum[tid];
            int wincl = wv;
#pragma unroll
            for (int d = 1; d < 16; d <<= 1) {
                int t = __shfl_up(wincl, d);
                if (tid >= d) wincl += t;
            }
            wsum[tid] = wincl - wv;
        }
        __syncthreads();
        if (tid < nb) {
            int ex = wsum[wid] + incl - v;
            excl[tid] = ex;
            lofs[tid] = ex;
        }
    }
    __syncthreads();

#pragma unroll
    for (int k = 0; k < EPT; ++k) {
        if (bk[k] >= 0) {
            int pos = atomicAdd(&lofs[bk[k]], 1);
            sorted[pos] = w[k];
        }
    }
    __syncthreads();

    // coalesced copy-out: one 16-lane group per bucket round-robin
    int g16 = tid >> 4, l16 = tid & 15;               // 64 groups
    for (int j = g16; j < nb; j += 64) {
        int c = cnt[j];
        if (!c) continue;
        int st = excl[j], gb = gbase[j];
        size_t go = (size_t)j * CAP;
        for (int l = l16; l < c; l += 16)
            if (gb + l < CAP) pairs[go + gb + l] = sorted[st + l];
    }
}

// ==================== per-bucket sort by local dst (no praw staging) ====================
__global__ __launch_bounds__(512) void sort_kernel(int* __restrict__ pairs,
                                                   const int* __restrict__ gcnt,
                                                   int* __restrict__ rs_g,
                                                   float* __restrict__ dinv, int n) {
    __shared__ int slist[CAP];               // 20KB
    __shared__ int cnt2[NPB * 2], lofs2[NPB * 2], rowstart[NPB];
    __shared__ int wtot_s;
    int tid = threadIdx.x, b = blockIdx.x;
    int cc = tid & 1;
    if (tid < NPB * 2) cnt2[tid] = 0;
    __syncthreads();

    int c = min(gcnt[b], CAP);
    size_t go = (size_t)b * CAP;

    // pass 1: histogram (global read, L2-resident)
    for (int i = tid; i < c; i += 512)
        atomicAdd(&cnt2[(pairs[go + i] >> SBITS) * 2 + cc], 1);
    __syncthreads();

    int v = 0, incl = 0;
    if (tid < NPB) {
        v = cnt2[tid * 2] + cnt2[tid * 2 + 1];
        incl = v;
        int lane = tid & 63;
#pragma unroll
        for (int d = 1; d < 64; d <<= 1) {
            int t = __shfl_up(incl, d);
            if (lane >= d) incl += t;
        }
        if (tid == 63) wtot_s = incl;
    }
    __syncthreads();
    if (tid < NPB) {
        int ex = incl - v + ((tid >= 64) ? wtot_s : 0);
        rowstart[tid] = ex;
        lofs2[tid * 2]     = ex;
        lofs2[tid * 2 + 1] = ex + cnt2[tid * 2];
    }
    __syncthreads();

    // pass 2: placement (global re-read, L2 hit)
    for (int i = tid; i < c; i += 512) {
        int w = pairs[go + i];
        int pos = atomicAdd(&lofs2[(w >> SBITS) * 2 + cc], 1);
        slist[pos] = w & SMASK;
    }
    __syncthreads();

    for (int i = tid; i < c; i += 512) pairs[go + i] = slist[i];
    if (tid < NPB) {
        rs_g[b * NPB + tid] = rowstart[tid];
        int node = b * NPB + tid;
        if (node < n) dinv[node] = rsqrtf((float)v + 1.0f);
    }
}

// ==================== GEMM1: h1h = half(x @ W1 * dinv[row]) ====================
__global__ __launch_bounds__(256) void gemm1_kernel(const float* __restrict__ x,
                                                    const float* __restrict__ W,
                                                    const float* __restrict__ dinv,
                                                    __half* __restrict__ h1h, int n,
                                                    int sentinel) {
    __shared__ float WsT[16 * 132];      // [f][k] stride 132 (8.4KB)
    int tid = threadIdx.x;
    int n0 = blockIdx.x * G1N;

    for (int i = tid; i < FIN * FMID; i += 256) {
        int k = i >> 4, f = i & 15;
        WsT[f * 132 + k] = W[i];
    }
    __syncthreads();

    int ngrp = tid >> 3;       // 0..31
    int fh = tid & 7;          // half2 slot; features 2fh, 2fh+1
    int r0 = n0 + ngrp, r1 = r0 + 32, r2 = r0 + 64, r3 = r0 + 96;
    int nc = n - 1;
    size_t c0 = (size_t)min(r0, nc) * 32;
    size_t c1 = (size_t)min(r1, nc) * 32;
    size_t c2 = (size_t)min(r2, nc) * 32;
    size_t c3 = (size_t)min(r3, nc) * 32;

    const float4* x4  = (const float4*)x;
    const float4* wa4 = (const float4*)(WsT + (2 * fh) * 132);
    const float4* wb4 = (const float4*)(WsT + (2 * fh + 1) * 132);

    float a0 = 0.f, a1 = 0.f, a2 = 0.f, a3 = 0.f;
    float b0 = 0.f, b1_ = 0.f, b2_ = 0.f, b3 = 0.f;

#pragma unroll 8
    for (int ck = 0; ck < 32; ++ck) {
        float4 x0 = x4[c0 + ck];
        float4 x1 = x4[c1 + ck];
        float4 x2 = x4[c2 + ck];
        float4 x3 = x4[c3 + ck];
        float4 wa = wa4[ck];
        float4 wb = wb4[ck];
        a0 += x0.x * wa.x + x0.y * wa.y + x0.z * wa.z + x0.w * wa.w;
        a1 += x1.x * wa.x + x1.y * wa.y + x1.z * wa.z + x1.w * wa.w;
        a2 += x2.x * wa.x + x2.y * wa.y + x2.z * wa.z + x2.w * wa.w;
        a3 += x3.x * wa.x + x3.y * wa.y + x3.z * wa.z + x3.w * wa.w;
        b0  += x0.x * wb.x + x0.y * wb.y + x0.z * wb.z + x0.w * wb.w;
        b1_ += x1.x * wb.x + x1.y * wb.y + x1.z * wb.z + x1.w * wb.w;
        b2_ += x2.x * wb.x + x2.y * wb.y + x2.z * wb.z + x2.w * wb.w;
        b3  += x3.x * wb.x + x3.y * wb.y + x3.z * wb.z + x3.w * wb.w;
    }

    float ra[4] = {a0, a1, a2, a3};
    float rb[4] = {b0, b1_, b2_, b3};
    int rr[4] = {r0, r1, r2, r3};
    __half2* h2 = (__half2*)h1h;
#pragma unroll
    for (int i = 0; i < 4; ++i) {
        int node = rr[i];
        if (node < n) {
            float dd = dinv ? dinv[node] : 1.0f;
            h2[(size_t)node * 8 + fh] = __floats2half2_rn(ra[i] * dd, rb[i] * dd);
        } else if (node == n && sentinel) {
            h2[(size_t)n * 8 + fh] = __floats2half2_rn(0.0f, 0.0f);
        }
    }
}

// ==================== scatter1: fp16 gather + fused epilogue ====================
__global__ __launch_bounds__(512) void scatter1_kernel(const int* __restrict__ pairs,
                                                       const int* __restrict__ gcnt,
                                                       const int* __restrict__ rs_g,
                                                       const float* __restrict__ dinv,
                                                       const __half* __restrict__ h1h,
                                                       const float* __restrict__ b1,
                                                       const float* __restrict__ W2,
                                                       __half* __restrict__ h3h, int n) {
    __shared__ int   slist[CAP + 8];
    __shared__ int   rowstart_s[NPB + 1];
    __shared__ float acc2[NPB * AS1];        // stride 17
    __shared__ float W2s[FMID * FOUT];
    __shared__ float b1s[FMID];
    int tid = threadIdx.x, b = blockIdx.x;
    int c = min(gcnt[b], CAP);
    size_t go = (size_t)b * CAP;

    if (tid < FMID * FOUT) W2s[tid] = W2[tid];
    if (tid < FMID) b1s[tid] = b1[tid];
    if (tid < NPB) rowstart_s[tid] = rs_g[b * NPB + tid];
    if (tid == 0) rowstart_s[NPB] = c;
    for (int i = tid; i < c; i += 512) slist[i] = pairs[go + i];
    __syncthreads();

    {
        int nd = tid >> 2, l = tid & 3;
        int eo = l >> 1, half = l & 1;
        int pbeg = rowstart_s[nd];
        int pend = rowstart_s[nd + 1];
        const float4* h4 = (const float4*)h1h;   // 2 x 16B per 32B row
        float acc[8];
#pragma unroll
        for (int k = 0; k < 8; ++k) acc[k] = 0.0f;
        for (int p = pbeg + eo; p < pend; p += 8) {
            int i0 = slist[p];
            int i1 = (p + 2 < pend) ? slist[p + 2] : n;
            int i2 = (p + 4 < pend) ? slist[p + 4] : n;
            int i3 = (p + 6 < pend) ? slist[p + 6] : n;
            float4 v0 = h4[(size_t)i0 * 2 + half];
            float4 v1 = h4[(size_t)i1 * 2 + half];
            float4 v2 = h4[(size_t)i2 * 2 + half];
            float4 v3 = h4[(size_t)i3 * 2 + half];
            addh8(acc, v0);
            addh8(acc, v1);
            addh8(acc, v2);
            addh8(acc, v3);
        }
#pragma unroll
        for (int k = 0; k < 8; ++k) acc[k] += __shfl_xor(acc[k], 2);
        if (eo == 0) {
            float* ap = acc2 + nd * AS1 + half * 8;
#pragma unroll
            for (int k = 0; k < 8; ++k) ap[k] = acc[k];
        }
    }
    __syncthreads();

    int node = b * NPB + tid;
    if (tid < NPB && node < n) {
        float dd = dinv[node];
        float4 sr0 = ((const float4*)h1h)[(size_t)node * 2 + 0];
        float4 sr1 = ((const float4*)h1h)[(size_t)node * 2 + 1];
        float fself[FMID];
        {
            const __half2* ha = (const __half2*)&sr0;
            const __half2* hb = (const __half2*)&sr1;
#pragma unroll
            for (int k = 0; k < 4; ++k) {
                float2 fa = __half22float2(ha[k]);
                float2 fb = __half22float2(hb[k]);
                fself[2 * k]     = fa.x;
                fself[2 * k + 1] = fa.y;
                fself[8 + 2 * k]     = fb.x;
                fself[8 + 2 * k + 1] = fb.y;
            }
        }
        float vbuf[FMID];
#pragma unroll
        for (int k = 0; k < FMID; ++k) {
            float t = dd * (acc2[tid * AS1 + k] + fself[k]) + b1s[k];
            vbuf[k] = t > 0.0f ? t : 0.0f;
        }
        float sj[8];
#pragma unroll
        for (int j = 0; j < FOUT; ++j) {
            float s = 0.0f;
#pragma unroll
            for (int k = 0; k < FMID; ++k) s += vbuf[k] * W2s[k * FOUT + j];
            sj[j] = s * dd;
        }
        float4 st;
        __half2* sp = (__half2*)&st;
        sp[0] = __floats2half2_rn(sj[0], sj[1]);
        sp[1] = __floats2half2_rn(sj[2], sj[3]);
        sp[2] = __floats2half2_rn(sj[4], sj[5]);
        sp[3] = __floats2half2_rn(sj[6], 0.0f);
        ((float4*)h3h)[node] = st;               // 16B row
    } else if (tid < NPB && node == n) {
        ((float4*)h3h)[n] = make_float4(0.f, 0.f, 0.f, 0.f);
    }
}

// ==================== scatter2: fp16 gather + log_softmax ====================
__global__ __launch_bounds__(512) void scatter2_kernel(const int* __restrict__ pairs,
                                                       const int* __restrict__ gcnt,
                                                       const int* __restrict__ rs_g,
                                                       const float* __restrict__ dinv,
                                                       const __half* __restrict__ h3h,
                                                       const float* __restrict__ b2,
                                                       float* __restrict__ out, int n) {
    __shared__ int   slist[CAP + 8];
    __shared__ int   rowstart_s[NPB + 1];
    __shared__ float acc2[NPB * AS2];        // stride 9
    __shared__ float b2s[8];
    int tid = threadIdx.x, b = blockIdx.x;
    int c = min(gcnt[b], CAP);
    size_t go = (size_t)b * CAP;

    if (tid < FOUT) b2s[tid] = b2[tid];
    if (tid < NPB) rowstart_s[tid] = rs_g[b * NPB + tid];
    if (tid == 0) rowstart_s[NPB] = c;
    for (int i = tid; i < c; i += 512) slist[i] = pairs[go + i];
    __syncthreads();

    {
        int nd = tid >> 2, l = tid & 3;
        int pbeg = rowstart_s[nd];
        int pend = rowstart_s[nd + 1];
        const float4* h4 = (const float4*)h3h;   // 16B per row
        float acc[8];
#pragma unroll
        for (int k = 0; k < 8; ++k) acc[k] = 0.0f;
        for (int p = pbeg + l; p < pend; p += 8) {
            int i0 = slist[p];
            int i1 = (p + 4 < pend) ? slist[p + 4] : n;
            float4 v0 = h4[i0];
            float4 v1 = h4[i1];
            addh8(acc, v0);
            addh8(acc, v1);
        }
#pragma unroll
        for (int k = 0; k < 8; ++k) {
            acc[k] += __shfl_xor(acc[k], 1);
            acc[k] += __shfl_xor(acc[k], 2);
        }
        if (l == 0) {
            float* ap = acc2 + nd * AS2;
#pragma unroll
            for (int k = 0; k < 8; ++k) ap[k] = acc[k];
        }
    }
    __syncthreads();

    int node = b * NPB + tid;
    if (tid < NPB && node < n) {
        float dd = dinv[node];
        float4 sv = ((const float4*)h3h)[node];
        float hself[8];
        {
            const __half2* h = (const __half2*)&sv;
#pragma unroll
            for (int k = 0; k < 4; ++k) {
                float2 f2v = __half22float2(h[k]);
                hself[2 * k] = f2v.x;
                hself[2 * k + 1] = f2v.y;
            }
        }
        float t[FOUT], m = -INFINITY;
#pragma unroll
        for (int j = 0; j < FOUT; ++j) {
            t[j] = dd * (acc2[tid * AS2 + j] + hself[j]) + b2s[j];
            m = fmaxf(m, t[j]);
        }
        float sum = 0.0f;
#pragma unroll
        for (int j = 0; j < FOUT; ++j) sum += expf(t[j] - m);
        float lse = logf(sum);
#pragma unroll
        for (int j = 0; j < FOUT; ++j) out[(size_t)node * FOUT + j] = t[j] - m - lse;
    }
}

// ==================== fallback (fp32 atomic path) ====================
__global__ void fb_gemm1_kernel(const float* __restrict__ x, const float* __restrict__ W,
                                float* __restrict__ h1, int n) {
    int i = blockIdx.x * blockDim.x + threadIdx.x;
    if (i >= n * FMID) return;
    int node = i >> 4, f = i & 15;
    float s = 0.0f;
    for (int k = 0; k < FIN; ++k) s += x[(size_t)node * FIN + k] * W[k * FMID + f];
    h1[i] = s;
}
__global__ void fb_deg_kernel(const int* __restrict__ dst, float* __restrict__ deg, int e) {
    int i = blockIdx.x * blockDim.x + threadIdx.x;
    if (i < e) atomicAdd(&deg[dst[i]], 1.0f);
}
__global__ void fb_dinv_kernel(float* __restrict__ deg, int n) {
    int i = blockIdx.x * blockDim.x + threadIdx.x;
    if (i < n) deg[i] = rsqrtf(deg[i] + 1.0f);
}
__global__ void fb_scatter1_kernel(const int* __restrict__ src, const int* __restrict__ dst,
                                   const float* __restrict__ dinv, const float* __restrict__ h1,
                                   float* __restrict__ out1, int e) {
    int i = blockIdx.x * blockDim.x + threadIdx.x;
    if (i >= e) return;
    int s = src[i], d = dst[i];
    float norm = dinv[s] * dinv[d];
    const float4* hs = (const float4*)(h1 + (size_t)s * FMID);
    float* o = out1 + (size_t)d * FMID;
#pragma unroll
    for (int q = 0; q < 4; ++q) {
        float4 vv = hs[q];
        atomicAdd(o + q * 4 + 0, vv.x * norm);
        atomicAdd(o + q * 4 + 1, vv.y * norm);
        atomicAdd(o + q * 4 + 2, vv.z * norm);
        atomicAdd(o + q * 4 + 3, vv.w * norm);
    }
}
__global__ void fb_layer2_kernel(const float* __restrict__ agg, const float* __restrict__ h1,
                                 const float* __restrict__ dinv, const float* __restrict__ b1,
                                 const float* __restrict__ W2, float* __restrict__ h3, int n) {
    int i = blockIdx.x * blockDim.x + threadIdx.x;
    if (i >= n) return;
    float dii = dinv[i] * dinv[i];
    float v[FMID];
#pragma unroll
    for (int k = 0; k < FMID; ++k) {
        float t = agg[(size_t)i * FMID + k] + h1[(size_t)i * FMID + k] * dii + b1[k];
        v[k] = t > 0.0f ? t : 0.0f;
    }
#pragma unroll
    for (int j = 0; j < FOUT; ++j) {
        float s = 0.0f;
#pragma unroll
        for (int k = 0; k < FMID; ++k) s += v[k] * W2[k * FOUT + j];
        h3[(size_t)i * FOUT + j] = s;
    }
}
__global__ void fb_scatter2_kernel(const int* __restrict__ src, const int* __restrict__ dst,
                                   const float* __restrict__ dinv, const float* __restrict__ h3,
                                   float* __restrict__ out2, int e) {
    int i = blockIdx.x * blockDim.x + threadIdx.x;
    if (i >= e) return;
    int s = src[i], d = dst[i];
    float norm = dinv[s] * dinv[d];
    const float* hs = h3 + (size_t)s * FOUT;
    float* o = out2 + (size_t)d * FOUT;
#pragma unroll
    for (int j = 0; j < FOUT; ++j) atomicAdd(o + j, hs[j] * norm);
}
__global__ void fb_finalize_kernel(const float* __restrict__ agg2, const float* __restrict__ h3,
                                   const float* __restrict__ dinv, const float* __restrict__ b2,
                                   float* __restrict__ out, int n) {
    int i = blockIdx.x * blockDim.x + threadIdx.x;
    if (i >= n) return;
    float dii = dinv[i] * dinv[i];
    float t[FOUT], m = -INFINITY;
#pragma unroll
    for (int j = 0; j < FOUT; ++j) {
        t[j] = agg2[(size_t)i * FOUT + j] + h3[(size_t)i * FOUT + j] * dii + b2[j];
        m = fmaxf(m, t[j]);
    }
    float sum = 0.0f;
#pragma unroll
    for (int j = 0; j < FOUT; ++j) sum += expf(t[j] - m);
    float lse = logf(sum);
#pragma unroll
    for (int j = 0; j < FOUT; ++j) out[(size_t)i * FOUT + j] = t[j] - m - lse;
}

extern "C" void kernel_launch(void* const* d_in, const int* in_sizes, int n_in,
                              void* d_out, int out_size, void* d_ws, size_t ws_size,
                              hipStream_t stream) {
    const float* x  = (const float*)d_in[0];
    const int*   ei = (const int*)d_in[1];
    const float* W1 = (const float*)d_in[2];
    const float* b1 = (const float*)d_in[3];
    const float* W2 = (const float*)d_in[4];
    const float* b2 = (const float*)d_in[5];

    const int n = in_sizes[0] / FIN;   // 100000
    const int e = in_sizes[1] / 2;     // 3200000
    const int* src = ei;
    const int* dst = ei + e;

    const int nb  = (n + NPB - 1) / NPB;
    const int nb2 = (n + 1 + NPB - 1) / NPB;

    size_t need = ((size_t)NB_MAX + (size_t)nb * CAP + (size_t)n +
                   (size_t)nb2 * NPB + (size_t)8 * (n + 1) + (size_t)4 * (n + 1)) * 4;

    if (nb2 <= NB_MAX && n + 1 < (1 << SBITS) && ws_size >= need) {
        int*    gcnt  = (int*)d_ws;
        int*    pairs = gcnt + NB_MAX;
        float*  dinv  = (float*)(pairs + (size_t)nb * CAP);
        int*    rs_g  = (int*)(dinv + n);
        __half* h1h   = (__half*)(rs_g + (size_t)nb2 * NPB);
        __half* h3h   = h1h + (size_t)16 * (n + 1);

        zero_kernel<<<(NB_MAX + 255) / 256, 256, 0, stream>>>(gcnt, NB_MAX);

        int gridBin = (e + TILE - 1) / TILE;
        bin_kernel<<<gridBin, BINT, 0, stream>>>(src, dst, pairs, gcnt, e, nb);
        sort_kernel<<<nb, 512, 0, stream>>>(pairs, gcnt, rs_g, dinv, n);
        gemm1_kernel<<<nb2, 256, 0, stream>>>(x, W1, dinv, h1h, n, 1);
        scatter1_kernel<<<nb2, 512, 0, stream>>>(pairs, gcnt, rs_g, dinv, h1h, b1, W2, h3h, n);
        scatter2_kernel<<<nb, 512, 0, stream>>>(pairs, gcnt, rs_g, dinv, h3h, b2, (float*)d_out, n);
    } else {
        // fallback: fp32 atomic path (47n floats)
        float* ws   = (float*)d_ws;
        float* deg  = ws;
        float* out1 = ws + (size_t)n;
        float* out2 = ws + (size_t)17 * n;
        float* h1   = ws + (size_t)24 * n;
        float* h3   = ws + (size_t)40 * n;

        hipMemsetAsync(ws, 0, (size_t)24 * n * sizeof(float), stream);

        const int B = 256;
        const int gridE = (e + B - 1) / B;
        const int gridN = (n + B - 1) / B;
        fb_deg_kernel<<<gridE, B, 0, stream>>>(dst, deg, e);
        fb_dinv_kernel<<<gridN, B, 0, stream>>>(deg, n);
        fb_gemm1_kernel<<<(n * FMID + B - 1) / B, B, 0, stream>>>(x, W1, h1, n);
        fb_scatter1_kernel<<<gridE, B, 0, stream>>>(src, dst, deg, h1, out1, e);
        fb_layer2_kernel<<<gridN, B, 0, stream>>>(out1, h1, deg, b1, W2, h3, n);
        fb_scatter2_kernel<<<gridE, B, 0, stream>>>(src, dst, deg, h3, out2, e);
        fb_finalize_kernel<<<gridN, B, 0, stream>>>(out2, h3, deg, b2, (float*)d_out, n);
    }
}